// Round 1
// baseline (1617.345 us; speedup 1.0000x reference)
//
#include <hip/hip_runtime.h>

#define NVV 4096
#define NCC 16384

typedef __attribute__((ext_vector_type(8))) short short8;
typedef __attribute__((ext_vector_type(4))) float f32x4;

__device__ __forceinline__ short f2bf(float f) {
  union { float f; unsigned u; } v; v.f = f;
  unsigned r = v.u + 0x7fffu + ((v.u >> 16) & 1u);
  return (short)(r >> 16);
}

template<typename AT>
__device__ __forceinline__ short8 load8v(const AT* p) {
  if constexpr (sizeof(AT) == 2) {
    return *(const short8*)p;
  } else {
    const f32x4* q = (const f32x4*)p;
    f32x4 a = q[0], b = q[1];
    short8 o;
#pragma unroll
    for (int j = 0; j < 4; ++j) { o[j] = f2bf(a[j]); o[j + 4] = f2bf(b[j]); }
    return o;
  }
}

// fp32 -> bf16 bulk conversion (n8 = elements/8)
__global__ __launch_bounds__(256) void k_conv(const float* __restrict__ src,
                                              short* __restrict__ dst, int n8) {
  int i = blockIdx.x * blockDim.x + threadIdx.x;
  const int stride = gridDim.x * blockDim.x;
  for (; i < n8; i += stride) {
    const f32x4* q = (const f32x4*)(src + (size_t)i * 8);
    f32x4 a = q[0], b = q[1];
    short8 o;
#pragma unroll
    for (int j = 0; j < 4; ++j) { o[j] = f2bf(a[j]); o[j + 4] = f2bf(b[j]); }
    *(short8*)(dst + (size_t)i * 8) = o;
  }
}

// Small MLP: out[n][m] = sum_j [labels|embs][m][j] * W[j][n]  (writes TRANSPOSED bf16)
// labels [Nrows][8], embs [Nrows][128] f32 (ignored if FIRST), W [136][128]
template<bool FIRST, int NROW>
__global__ __launch_bounds__(128) void k_mlp(
    const float* __restrict__ labels, const float* __restrict__ embs,
    const float* __restrict__ Wp, const float* __restrict__ Wn,
    short* __restrict__ Tp, short* __restrict__ Tn, int Nrows) {
  const int n = threadIdx.x;
  const int m0 = blockIdx.x * NROW;
  float ap[NROW] = {}, an[NROW] = {};
  const int JMAX = FIRST ? 8 : 136;
  for (int j = 0; j < JMAX; ++j) {
    const float wp = Wp[j * 128 + n], wn = Wn[j * 128 + n];
#pragma unroll
    for (int r = 0; r < NROW; ++r) {
      const float x = (j < 8) ? labels[(size_t)(m0 + r) * 8 + j]
                              : embs[(size_t)(m0 + r) * 128 + (j - 8)];
      ap[r] = fmaf(x, wp, ap[r]);
      an[r] = fmaf(x, wn, an[r]);
    }
  }
#pragma unroll
  for (int r = 0; r < NROW; ++r) {
    Tp[(size_t)n * Nrows + m0 + r] = f2bf(ap[r]);
    Tn[(size_t)n * Nrows + m0 + r] = f2bf(an[r]);
  }
}

// C[m][n] = sum_k A[m][k]*Bp[k][n] + Aneg[m][k]*Bn[k][n]
// TRANSA=0: A element at Ap[m*lda + k]; TRANSA=1: Ap[k*lda + m].
// B given transposed: Bp[n*ldb + k] (bf16).
// EPI=0: C = relu(acc + bias), f32 [M][128].  EPI=1: partial f32 at C[z*M*128 + ...].
// Tiles: BM=32, BN=64, BK=64; 256 threads = 4 waves (1m x 4n), wave tile 32x16.
template<typename AT, bool TRANSA, int EPI>
__global__ __launch_bounds__(256) void k_gemm(
    const AT* __restrict__ Ap, const AT* __restrict__ An,
    const short* __restrict__ Bp, const short* __restrict__ Bn,
    const float* __restrict__ bias, float* __restrict__ C,
    int M, int lda, int ldb, int Klen) {
  __shared__ __align__(16) short sA[2][32 * 64];
  __shared__ __align__(16) short sB[2][64 * 64];
  const int tid = threadIdx.x;
  const int w = tid >> 6, l = tid & 63, lr = l & 15, lh = l >> 4;
  const int m0 = blockIdx.x * 32, n0 = blockIdx.y * 64;
  const int Koff = blockIdx.z * Klen;
  f32x4 acc0 = {0.f, 0.f, 0.f, 0.f}, acc1 = {0.f, 0.f, 0.f, 0.f};

  for (int step = 0; step < (Klen >> 6); ++step) {
    const int k0 = Koff + (step << 6);
    __syncthreads();
    if (!TRANSA) {
      const int m = tid >> 3, kc = tid & 7;
      const size_t ga = (size_t)(m0 + m) * lda + k0 + (kc << 3);
      const int ad = (m << 6) + ((kc ^ (m & 7)) << 3);
      *(short8*)&sA[0][ad] = load8v(Ap + ga);
      *(short8*)&sA[1][ad] = load8v(An + ga);
    } else {
      const int r = tid >> 2, c8 = (tid & 3) << 3;
      const size_t ga = (size_t)(k0 + r) * lda + m0 + c8;
      short8 vp = load8v(Ap + ga), vn = load8v(An + ga);
#pragma unroll
      for (int j = 0; j < 8; ++j) {
        const int m = c8 + j;
        const int ad = (m << 6) + ((((r >> 3)) ^ (m & 7)) << 3) + (r & 7);
        sA[0][ad] = vp[j];
        sA[1][ad] = vn[j];
      }
    }
#pragma unroll
    for (int i = 0; i < 2; ++i) {
      const int c = (i << 8) + tid;  // 0..511
      const int n = c >> 3, kc = c & 7;
      const size_t gb = (size_t)(n0 + n) * ldb + k0 + (kc << 3);
      const int ad = (n << 6) + ((kc ^ (n & 7)) << 3);
      *(short8*)&sB[0][ad] = *(const short8*)(Bp + gb);
      *(short8*)&sB[1][ad] = *(const short8*)(Bn + gb);
    }
    __syncthreads();
#pragma unroll
    for (int kh = 0; kh < 2; ++kh) {
      const int kc = (kh << 2) + lh;
      const int bn_ = (w << 4) + lr;
      short8 bp = *(short8*)&sB[0][(bn_ << 6) + ((kc ^ (bn_ & 7)) << 3)];
      short8 bnv = *(short8*)&sB[1][(bn_ << 6) + ((kc ^ (bn_ & 7)) << 3)];
      short8 a0p = *(short8*)&sA[0][(lr << 6) + ((kc ^ (lr & 7)) << 3)];
      short8 a0n = *(short8*)&sA[1][(lr << 6) + ((kc ^ (lr & 7)) << 3)];
      const int m1 = 16 + lr;
      short8 a1p = *(short8*)&sA[0][(m1 << 6) + ((kc ^ (m1 & 7)) << 3)];
      short8 a1n = *(short8*)&sA[1][(m1 << 6) + ((kc ^ (m1 & 7)) << 3)];
      acc0 = __builtin_amdgcn_mfma_f32_16x16x32_bf16(a0p, bp, acc0, 0, 0, 0);
      acc0 = __builtin_amdgcn_mfma_f32_16x16x32_bf16(a0n, bnv, acc0, 0, 0, 0);
      acc1 = __builtin_amdgcn_mfma_f32_16x16x32_bf16(a1p, bp, acc1, 0, 0, 0);
      acc1 = __builtin_amdgcn_mfma_f32_16x16x32_bf16(a1n, bnv, acc1, 0, 0, 0);
    }
  }
  const int n = n0 + (w << 4) + lr;
#pragma unroll
  for (int mf = 0; mf < 2; ++mf) {
    f32x4 a = mf ? acc1 : acc0;
#pragma unroll
    for (int r = 0; r < 4; ++r) {
      const int m = m0 + (mf << 4) + (lh << 2) + r;
      float c = a[r];
      if (EPI == 0) {
        c += bias[n];
        c = fmaxf(c, 0.f);
        C[(size_t)m * 128 + n] = c;
      } else {
        C[((size_t)blockIdx.z * M + m) * 128 + n] = c;
      }
    }
  }
}

// sum 4 split-K partials + bias -> relu -> LayerNorm -> out (f32). One wave per row.
__global__ __launch_bounds__(256) void k_reduce_ln(
    const float* __restrict__ part, const float* __restrict__ bias,
    const float* __restrict__ gamma, const float* __restrict__ beta,
    float* __restrict__ out) {
  const int w = threadIdx.x >> 6, l = threadIdx.x & 63;
  const int m = blockIdx.x * 4 + w;
  const int n0 = l << 1;
  float x0 = bias[n0], x1 = bias[n0 + 1];
#pragma unroll
  for (int ks = 0; ks < 4; ++ks) {
    const size_t o = ((size_t)ks * NVV + m) * 128 + n0;
    x0 += part[o];
    x1 += part[o + 1];
  }
  x0 = fmaxf(x0, 0.f);
  x1 = fmaxf(x1, 0.f);
  float s = x0 + x1, q = x0 * x0 + x1 * x1;
#pragma unroll
  for (int off = 32; off; off >>= 1) {
    s += __shfl_xor(s, off);
    q += __shfl_xor(q, off);
  }
  const float mu = s * (1.f / 128.f);
  const float var = q * (1.f / 128.f) - mu * mu;
  const float inv = 1.f / sqrtf(var + 1e-5f);
  out[(size_t)m * 128 + n0]     = (x0 - mu) * inv * gamma[n0] + beta[n0];
  out[(size_t)m * 128 + n0 + 1] = (x1 - mu) * inv * gamma[n0 + 1] + beta[n0 + 1];
}

extern "C" void kernel_launch(void* const* d_in, const int* in_sizes, int n_in,
                              void* d_out, int out_size, void* d_ws, size_t ws_size,
                              hipStream_t stream) {
  const float* vlabels  = (const float*)d_in[0];
  const float* clabels  = (const float*)d_in[1];
  const float* cmat_pos = (const float*)d_in[2];
  const float* cmat_neg = (const float*)d_in[3];
  const float* Wvp = (const float*)d_in[4];
  const float* Wvn = (const float*)d_in[5];
  const float* Bv  = (const float*)d_in[6];
  const float* Wcp = (const float*)d_in[7];
  const float* Wcn = (const float*)d_in[8];
  const float* Bc  = (const float*)d_in[9];
  const float* gam = (const float*)d_in[10];
  const float* bet = (const float*)d_in[11];
  float* out = (float*)d_out;

  char* base = (char*)d_ws;
  size_t off = 0;
  auto carve = [&](size_t b) -> void* {
    void* p = base + off;
    off += (b + 255) & ~(size_t)255;
    return p;
  };
  short* pvT  = (short*)carve((size_t)128 * NVV * 2);
  short* nvT  = (short*)carve((size_t)128 * NVV * 2);
  short* pcT  = (short*)carve((size_t)128 * NCC * 2);
  short* ncT  = (short*)carve((size_t)128 * NCC * 2);
  float* cemb = (float*)carve((size_t)NCC * 128 * 4);
  float* part = (float*)carve((size_t)4 * NVV * 128 * 4);
  short* cmPb = (short*)carve((size_t)NCC * NVV * 2);
  short* cmNb = (short*)carve((size_t)NCC * NVV * 2);
  const bool big = ws_size >= off;  // enough ws for bf16 adjacency copies?

  if (big) {
    k_conv<<<4096, 256, 0, stream>>>(cmat_pos, cmPb, NCC * NVV / 8);
    k_conv<<<4096, 256, 0, stream>>>(cmat_neg, cmNb, NCC * NVV / 8);
  }

  for (int it = 0; it < 4; ++it) {
    if (it == 0)
      k_mlp<true, 16><<<NVV / 16, 128, 0, stream>>>(vlabels, nullptr, Wvp, Wvn, pvT, nvT, NVV);
    else
      k_mlp<false, 16><<<NVV / 16, 128, 0, stream>>>(vlabels, out, Wvp, Wvn, pvT, nvT, NVV);

    if (big)
      k_gemm<short, false, 0><<<dim3(NCC / 32, 2, 1), 256, 0, stream>>>(
          cmPb, cmNb, pvT, nvT, Bv, cemb, NCC, NVV, NVV, NVV);
    else
      k_gemm<float, false, 0><<<dim3(NCC / 32, 2, 1), 256, 0, stream>>>(
          cmat_pos, cmat_neg, pvT, nvT, Bv, cemb, NCC, NVV, NVV, NVV);

    k_mlp<false, 16><<<NCC / 16, 128, 0, stream>>>(clabels, cemb, Wcp, Wcn, pcT, ncT, NCC);

    if (big)
      k_gemm<short, true, 1><<<dim3(NVV / 32, 2, 4), 256, 0, stream>>>(
          cmPb, cmNb, pcT, ncT, nullptr, part, NVV, NVV, NCC, NVV);
    else
      k_gemm<float, true, 1><<<dim3(NVV / 32, 2, 4), 256, 0, stream>>>(
          cmat_pos, cmat_neg, pcT, ncT, nullptr, part, NVV, NVV, NCC, NVV);

    k_reduce_ln<<<NVV / 4, 256, 0, stream>>>(part, Bc, gam, bet, out);
  }
}